// Round 7
// baseline (395.479 us; speedup 1.0000x reference)
//
#include <hip/hip_runtime.h>
#include <hip/hip_bf16.h>
#include <stdint.h>

#define MDIM 4096
#define NDIM 4096
#define KDIM 4096
#define NT 192   // effective K = 12288 over 3 bf16 segments, BK = 64

typedef float f32x4 __attribute__((ext_vector_type(4)));
typedef float f32x16 __attribute__((ext_vector_type(16)));
typedef short s16x8 __attribute__((ext_vector_type(8)));

__device__ __forceinline__ unsigned short f2bf(float x) {
  uint32_t u = __float_as_uint(x);
  uint32_t r = (u + 0x7fffu + ((u >> 16) & 1u)) >> 16;  // RNE
  return (unsigned short)r;
}
__device__ __forceinline__ float bf2f(unsigned short b) {
  return __uint_as_float(((uint32_t)b) << 16);
}

// ---------------- pre-pass 1: split A -> A_hi, A_lo (bf16 [M][K])
__global__ __launch_bounds__(256) void split_a(const float* __restrict__ A,
                                               unsigned short* __restrict__ hi,
                                               unsigned short* __restrict__ lo) {
  size_t i = ((size_t)blockIdx.x * 256 + threadIdx.x) * 4;
  float4 v = *(const float4*)(A + i);
  ushort4 h, l;
  h.x = f2bf(v.x); l.x = f2bf(v.x - bf2f(h.x));
  h.y = f2bf(v.y); l.y = f2bf(v.y - bf2f(h.y));
  h.z = f2bf(v.z); l.z = f2bf(v.z - bf2f(h.z));
  h.w = f2bf(v.w); l.w = f2bf(v.w - bf2f(h.w));
  *(ushort4*)(hi + i) = h;
  *(ushort4*)(lo + i) = l;
}

// ---------------- pre-pass 2: split + transpose B -> B_hiT, B_loT (bf16 [N][K])
__global__ __launch_bounds__(256) void split_bt(const float* __restrict__ B,
                                                unsigned short* __restrict__ hiT,
                                                unsigned short* __restrict__ loT) {
  __shared__ float tile[32][33];
  int n0 = blockIdx.x * 32, k0 = blockIdx.y * 32;
  int tx = threadIdx.x, ty = threadIdx.y;  // block (32,8)
#pragma unroll
  for (int i = 0; i < 32; i += 8)
    tile[ty + i][tx] = B[(size_t)(k0 + ty + i) * NDIM + n0 + tx];
  __syncthreads();
#pragma unroll
  for (int i = 0; i < 32; i += 8) {
    float x = tile[tx][ty + i];
    unsigned short h = f2bf(x);
    unsigned short l = f2bf(x - bf2f(h));
    size_t o = (size_t)(n0 + ty + i) * KDIM + k0 + tx;
    hiT[o] = h;
    loT[o] = l;
  }
}

// ---------------- main GEMM: 256x256, BK=64, 8 waves (2Mx4N), per-wave 128x64.
// 32x32x16 MFMA (4x2 frags), register-fragment pipeline: phase p reads slice
// p+1's frags, MFMAs slice p. 2 barriers + 2 counted vmcnt(2) per K-tile;
// ring-2 LDS 128 KiB, XOR-swizzled.
#define GLDS(gp, lp)                                              \
  __builtin_amdgcn_global_load_lds(                               \
      (const __attribute__((address_space(1))) void*)(gp),        \
      (__attribute__((address_space(3))) void*)(lp), 16, 0, 0)

#define BARRIER() asm volatile("s_barrier" ::: "memory")
#define WAITVM2() asm volatile("s_waitcnt vmcnt(2)" ::: "memory")
#define WAITVM0() asm volatile("s_waitcnt vmcnt(0)" ::: "memory")

#define RD_A(dst, cb, soff)                                                      \
  _Pragma("unroll")                                                              \
  for (int m = 0; m < 4; ++m)                                                    \
    dst[m] = *(const s16x8*)(lds_ + (cb) + laneA32 + m * 2048 + (soff))
#define RD_B(dst, cb, soff)                                                      \
  _Pragma("unroll")                                                              \
  for (int n = 0; n < 2; ++n)                                                    \
    dst[n] = *(const s16x8*)(lds_ + (cb) + laneB32 + n * 2048 + (soff))

#define MFMA32(AV, BV)                                                           \
  __builtin_amdgcn_s_setprio(1);                                                 \
  _Pragma("unroll")                                                              \
  for (int m = 0; m < 4; ++m) {                                                  \
    _Pragma("unroll")                                                            \
    for (int n = 0; n < 2; ++n)                                                  \
      acc[m][n] =                                                                \
          __builtin_amdgcn_mfma_f32_32x32x16_bf16(AV[m], BV[n], acc[m][n], 0, 0, 0); \
  }                                                                              \
  __builtin_amdgcn_s_setprio(0)

__global__ __launch_bounds__(512, 2) void gemm_k3(
    const unsigned short* __restrict__ Ah, const unsigned short* __restrict__ Al,
    const unsigned short* __restrict__ BhT, const unsigned short* __restrict__ BlT,
    float* __restrict__ C) {
  __shared__ __align__(16) char lds_[131072];  // 128 KiB

  const int tid = threadIdx.x;
  const int l   = tid & 63;
  const int wv  = tid >> 6;   // 0..7
  const int wm  = wv >> 2;    // 0..1
  const int wn  = wv & 3;     // 0..3

  // bijective XCD swizzle (256 blocks)
  const int bid = blockIdx.x;
  const int swz = (bid & 7) * 32 + (bid >> 3);
  const int bm = swz >> 4, bn = swz & 15;

  // staging lane geometry (linear LDS dest; inverse-swizzled global src)
  const int lG     = (l & 7) ^ (l >> 3);
  const int g_radd = 2 * (l >> 3) + (lG >> 2);
  const int g_col  = (lG & 3) * 16;
  const int row0a  = wv * 32;
  const int row0b  = wv * 32 + 16;

  // read lane geometry for 32x32x16 frags (same swizzle involution)
  const int fr32  = l & 31;
  const int hi32  = l >> 5;
  const int bslot = ((fr32 & 1) << 2) ^ ((fr32 >> 1) & 7);
  const int laneA32 = (wm * 64 + (fr32 >> 1)) * 128;
  const int laneB32 = 65536 + (wn * 32 + (fr32 >> 1)) * 128;
  // slice s (K=16): ks = s>>1, granule = (s&1)*2 + hi32; slot = bslot ^ granule
  const int so0 = ((bslot ^ (0 + hi32)) * 16);
  const int so1 = ((bslot ^ (2 + hi32)) * 16);
  const int so2 = 16384 + ((bslot ^ (0 + hi32)) * 16);
  const int so3 = 16384 + ((bslot ^ (2 + hi32)) * 16);

  const char* cAh = (const char*)Ah;
  const char* cAl = (const char*)Al;
  const char* cBh = (const char*)BhT;
  const char* cBl = (const char*)BlT;
  const size_t aoff = (size_t)(bm * 256) * 8192;
  const size_t boff = (size_t)(bn * 256) * 8192;

  f32x16 acc[4][2] = {};
  s16x8 aX[4], aY[4], bX[2], bY[2];

  // ---- prologue: stage tile 0 fully (order A0,B0,A1,B1), drain, read slice0 ----
  {
    const char* As = cAh + aoff;
    const char* Bs = cBh + boff;
    GLDS(As + (size_t)(row0a + g_radd) * 8192 + g_col, lds_ + row0a * 64);
    GLDS(As + (size_t)(row0b + g_radd) * 8192 + g_col, lds_ + row0b * 64);
    GLDS(Bs + (size_t)(row0a + g_radd) * 8192 + g_col, lds_ + 65536 + row0a * 64);
    GLDS(Bs + (size_t)(row0b + g_radd) * 8192 + g_col, lds_ + 65536 + row0b * 64);
    GLDS(As + (size_t)(row0a + g_radd) * 8192 + 64 + g_col, lds_ + 16384 + row0a * 64);
    GLDS(As + (size_t)(row0b + g_radd) * 8192 + 64 + g_col, lds_ + 16384 + row0b * 64);
    GLDS(Bs + (size_t)(row0a + g_radd) * 8192 + 64 + g_col, lds_ + 65536 + 16384 + row0a * 64);
    GLDS(Bs + (size_t)(row0b + g_radd) * 8192 + 64 + g_col, lds_ + 65536 + 16384 + row0b * 64);
  }
  WAITVM0();
  BARRIER();
  RD_A(aX, 0, so0);
  RD_B(bX, 0, so0);

  for (int t = 0; t < NT - 1; ++t) {
    const int cb = (t & 1) * 32768;
    const int Tn = t + 1;
    const char* An = ((Tn < 64) ? cAh : (Tn < 128) ? cAl : cAh) + aoff;
    const char* Bn = ((Tn < 128) ? cBh : cBl) + boff;
    const size_t kb = (size_t)(Tn & 63) * 128;
    char* dA = lds_ + (Tn & 1) * 32768;
    char* dB = dA + 65536;
    const int cb2 = (Tn & 1) * 32768;

    // ---- ph0: read slice1(t) -> Y; stage A-ks0(t+1); MFMA slice0 (X) ----
    RD_A(aY, cb, so1);
    RD_B(bY, cb, so1);
    GLDS(An + (size_t)(row0a + g_radd) * 8192 + kb + g_col, dA + row0a * 64);
    GLDS(An + (size_t)(row0b + g_radd) * 8192 + kb + g_col, dA + row0b * 64);
    MFMA32(aX, bX);

    // ---- ph1: drain ks1(t); read slice2(t) -> X; stage B-ks0(t+1); MFMA slice1 (Y)
    WAITVM2();
    BARRIER();
    RD_A(aX, cb, so2);
    RD_B(bX, cb, so2);
    GLDS(Bn + (size_t)(row0a + g_radd) * 8192 + kb + g_col, dB + row0a * 64);
    GLDS(Bn + (size_t)(row0b + g_radd) * 8192 + kb + g_col, dB + row0b * 64);
    MFMA32(aY, bY);

    // ---- ph2: read slice3(t) -> Y; stage A-ks1(t+1); MFMA slice2 (X) ----
    RD_A(aY, cb, so3);
    RD_B(bY, cb, so3);
    GLDS(An + (size_t)(row0a + g_radd) * 8192 + kb + 64 + g_col, dA + 16384 + row0a * 64);
    GLDS(An + (size_t)(row0b + g_radd) * 8192 + kb + 64 + g_col, dA + 16384 + row0b * 64);
    MFMA32(aX, bX);

    // ---- ph3: drain ks0(t+1); read slice0(t+1) -> X; stage B-ks1(t+1); MFMA slice3 (Y)
    WAITVM2();
    BARRIER();
    RD_A(aX, cb2, so0);
    RD_B(bX, cb2, so0);
    GLDS(Bn + (size_t)(row0a + g_radd) * 8192 + kb + 64 + g_col, dB + 16384 + row0a * 64);
    GLDS(Bn + (size_t)(row0b + g_radd) * 8192 + kb + 64 + g_col, dB + 16384 + row0b * 64);
    MFMA32(aY, bY);
  }

  // ---- peeled tail: t = NT-1 (no staging, no next-tile reads) ----
  {
    const int cb = ((NT - 1) & 1) * 32768;
    // ph0
    RD_A(aY, cb, so1);
    RD_B(bY, cb, so1);
    MFMA32(aX, bX);
    // ph1 — drain this tile's ks1 units
    WAITVM0();
    BARRIER();
    RD_A(aX, cb, so2);
    RD_B(bX, cb, so2);
    MFMA32(aY, bY);
    // ph2
    RD_A(aY, cb, so3);
    RD_B(bY, cb, so3);
    MFMA32(aX, bX);
    // ph3
    MFMA32(aY, bY);
  }

  // ---- epilogue: 32x32 C/D layout col=lane&31, row=(reg&3)+8*(reg>>2)+4*(lane>>5)
  float* Cp = C + (size_t)(bm * 256 + wm * 128) * NDIM + (bn * 256 + wn * 64);
#pragma unroll
  for (int m = 0; m < 4; ++m)
#pragma unroll
    for (int n = 0; n < 2; ++n)
#pragma unroll
      for (int r = 0; r < 16; ++r) {
        const int row = m * 32 + (r & 3) + 8 * (r >> 2) + 4 * hi32;
        Cp[(size_t)row * NDIM + n * 32 + fr32] = acc[m][n][r];
      }
}

// ---------------- fallback: plain fp32 tiled GEMM (ws too small) ----------------
__global__ __launch_bounds__(1024) void gemm_fp32_fallback(const float* __restrict__ A,
                                                           const float* __restrict__ B,
                                                           float* __restrict__ C) {
  __shared__ float As[32][33];
  __shared__ float Bs[32][33];
  int tx = threadIdx.x, ty = threadIdx.y;
  int row = blockIdx.y * 32 + ty, colg = blockIdx.x * 32 + tx;
  float acc = 0.f;
  for (int k0 = 0; k0 < KDIM; k0 += 32) {
    As[ty][tx] = A[(size_t)row * KDIM + k0 + tx];
    Bs[ty][tx] = B[(size_t)(k0 + ty) * NDIM + colg];
    __syncthreads();
#pragma unroll 8
    for (int kk = 0; kk < 32; ++kk) acc += As[ty][kk] * Bs[kk][tx];
    __syncthreads();
  }
  C[(size_t)row * NDIM + colg] = acc;
}

extern "C" void kernel_launch(void* const* d_in, const int* in_sizes, int n_in,
                              void* d_out, int out_size, void* d_ws, size_t ws_size,
                              hipStream_t stream) {
  const float* A = (const float*)d_in[0];
  const float* B = (const float*)d_in[1];
  float* C = (float*)d_out;

  const size_t elems = (size_t)MDIM * KDIM;
  const size_t need = 4 * elems * sizeof(unsigned short);  // 128 MB
  if (ws_size < need) {
    gemm_fp32_fallback<<<dim3(NDIM / 32, MDIM / 32), dim3(32, 32), 0, stream>>>(A, B, C);
    return;
  }

  unsigned short* Ah  = (unsigned short*)d_ws;
  unsigned short* Al  = Ah + elems;
  unsigned short* BhT = Al + elems;
  unsigned short* BlT = BhT + elems;

  split_a<<<(int)(elems / (256 * 4)), 256, 0, stream>>>(A, Ah, Al);
  split_bt<<<dim3(NDIM / 32, KDIM / 32), dim3(32, 8), 0, stream>>>(B, BhT, BlT);
  gemm_k3<<<dim3(256), dim3(512), 0, stream>>>(Ah, Al, BhT, BlT, C);
}